// Round 2
// baseline (175.527 us; speedup 1.0000x reference)
//
#include <hip/hip_runtime.h>

#define NB 16
#define NH 4
#define HD 128
#define HW 1024
#define CIN 512

typedef short s16x8 __attribute__((ext_vector_type(8)));
typedef short s16x4 __attribute__((ext_vector_type(4)));
typedef float f32x4 __attribute__((ext_vector_type(4)));

static __device__ __forceinline__ short f2bf(float f) {
    union { float f; unsigned u; } v; v.f = f;
    unsigned r = v.u + 0x7fffu + ((v.u >> 16) & 1u);   // round-to-nearest-even
    return (short)(r >> 16);
}

// ---------------------------------------------------------------------------
// prep: x[b][c][p] fp32 -> xT[b][p][c] bf16 (32x32 LDS tile transpose)
//       W[o][c]   fp32 -> Wb bf16 (elementwise)
// ---------------------------------------------------------------------------
__global__ __launch_bounds__(256) void prep_xw(
    const float* __restrict__ x, const float* __restrict__ w,
    short* __restrict__ xT, short* __restrict__ Wb)
{
    int blk = blockIdx.x;
    if (blk < NB * 16 * 32) {                  // 8192 transpose tiles
        int b = blk >> 9, rem = blk & 511;
        int ct = rem >> 5, pt = rem & 31;      // 16 c-tiles x 32 p-tiles
        __shared__ float tile[32][33];
        int tc = threadIdx.x >> 5;             // 0..7
        int tp = threadIdx.x & 31;             // 0..31
        const float* xb = x + ((size_t)b * CIN + ct * 32) * HW + pt * 32;
        #pragma unroll
        for (int i = 0; i < 4; i++)
            tile[tc + i * 8][tp] = xb[(size_t)(tc + i * 8) * HW + tp];
        __syncthreads();
        int p = threadIdx.x >> 3, cq = threadIdx.x & 7;
        short* xo = xT + ((size_t)b * HW + pt * 32 + p) * CIN + ct * 32 + cq * 4;
        s16x4 o4 = { f2bf(tile[cq * 4 + 0][p]), f2bf(tile[cq * 4 + 1][p]),
                     f2bf(tile[cq * 4 + 2][p]), f2bf(tile[cq * 4 + 3][p]) };
        *reinterpret_cast<s16x4*>(xo) = o4;
    } else {
        int wb = blk - NB * 16 * 32;           // 0..767, 1024 elems each
        size_t base = (size_t)wb * 1024 + threadIdx.x * 4;
        const float4 v = *reinterpret_cast<const float4*>(w + base);
        s16x4 o4 = { f2bf(v.x), f2bf(v.y), f2bf(v.z), f2bf(v.w) };
        *reinterpret_cast<s16x4*>(Wb + base) = o4;
    }
}

// ---------------------------------------------------------------------------
// qkv projection GEMM, BK=64, reg-prefetch pipelined. LDS re-laid to
// UNPADDED [128][64] + 16B-chunk XOR swizzle (phys = c ^ (row&7)):
// row stride 64 shorts = 32 words = 0 mod 32 -> every b128 access 2-way (free).
//   s=0: Q = val * (128^-0.5 * log2e)   [p][d]
//   s=1: K' = val + pos_h + pos_w       [p][d]
//   s=2: Vt = val                       [d][p]
// ---------------------------------------------------------------------------
__global__ __launch_bounds__(256, 3) void qkv_proj(
    const short* __restrict__ xT, const short* __restrict__ Wb,
    const float* __restrict__ pos_h, const float* __restrict__ pos_w,
    short* __restrict__ Q, short* __restrict__ Kp, short* __restrict__ Vt)
{
    __shared__ __align__(16) char smem[34816];
    short* As = (short*)smem;               // [128][64] swizzled
    short* Bs = As + 128 * 64;              // [128][64] swizzled
    short* vb = (short*)smem;               // [128][136] reused for V epilogue

    const int pt = blockIdx.x, ot = blockIdx.y, b = blockIdx.z;
    const int tid = threadIdx.x;
    const int wave = tid >> 6, lane = tid & 63;
    const int l16 = lane & 15, quad = lane >> 4;
    const int wm = (wave & 1) * 64, wn = (wave >> 1) * 64;
    const int o0 = ot * 128, p0 = pt * 128;

    const short* xb = xT + (size_t)b * HW * CIN;

    // staging: thread handles rows p*32 + r0 (p<4), chunk c0; row&7 = r0&7 const
    const int r0 = tid >> 3, c0 = tid & 7;
    const int sphys = c0 ^ (r0 & 7);
    const short* wp = Wb + (size_t)(o0 + r0) * CIN + c0 * 8;
    const short* xp = xb + (size_t)(p0 + r0) * CIN + c0 * 8;
    short* adst = As + r0 * 64 + sphys * 8;
    short* bdst = Bs + r0 * 64 + sphys * 8;

    f32x4 acc[4][4];
    #pragma unroll
    for (int i = 0; i < 4; i++)
        #pragma unroll
        for (int j = 0; j < 4; j++)
            acc[i][j] = f32x4{0.f, 0.f, 0.f, 0.f};

    s16x8 wreg[4], xreg[4];
    #pragma unroll
    for (int p = 0; p < 4; p++) {
        wreg[p] = *(const s16x8*)(wp + (size_t)(p * 32) * CIN);
        xreg[p] = *(const s16x8*)(xp + (size_t)(p * 32) * CIN);
    }

    #pragma unroll 1
    for (int kc = 0; kc < CIN; kc += 64) {
        #pragma unroll
        for (int p = 0; p < 4; p++) {
            *(s16x8*)(adst + p * 32 * 64) = wreg[p];
            *(s16x8*)(bdst + p * 32 * 64) = xreg[p];
        }
        __syncthreads();
        int kcn = (kc + 64) & (CIN - 1);       // wrap: last prefetch harmless
        #pragma unroll
        for (int p = 0; p < 4; p++) {
            wreg[p] = *(const s16x8*)(wp + kcn + (size_t)(p * 32) * CIN);
            xreg[p] = *(const s16x8*)(xp + kcn + (size_t)(p * 32) * CIN);
        }
        #pragma unroll
        for (int kk = 0; kk < 2; kk++) {
            s16x8 aF[4], bF[4];
            #pragma unroll
            for (int mi = 0; mi < 4; mi++)
                aF[mi] = *(const s16x8*)(As + (wm + mi * 16 + l16) * 64
                                         + (((kk * 4 + quad) ^ (l16 & 7)) * 8));
            #pragma unroll
            for (int ni = 0; ni < 4; ni++)
                bF[ni] = *(const s16x8*)(Bs + (wn + ni * 16 + l16) * 64
                                         + (((kk * 4 + quad) ^ (l16 & 7)) * 8));
            #pragma unroll
            for (int mi = 0; mi < 4; mi++)
                #pragma unroll
                for (int ni = 0; ni < 4; ni++)
                    acc[mi][ni] = __builtin_amdgcn_mfma_f32_16x16x32_bf16(
                        aF[mi], bF[ni], acc[mi][ni], 0, 0, 0);
        }
        __syncthreads();
    }

    const int s = ot >> 2, h = ot & 3;
    const size_t bh = (size_t)(b * NH + h);

    if (s == 0) {
        const float qs = 0.08838834764831845f * 1.4426950408889634f; // scale*log2e
        short* Qb = Q + bh * (size_t)(HW * HD);
        #pragma unroll
        for (int mi = 0; mi < 4; mi++) {
            int d0 = wm + mi * 16 + quad * 4;
            #pragma unroll
            for (int ni = 0; ni < 4; ni++) {
                int p = p0 + wn + ni * 16 + l16;
                f32x4 a = acc[mi][ni];
                s16x4 o4 = { f2bf(a.x * qs), f2bf(a.y * qs),
                             f2bf(a.z * qs), f2bf(a.w * qs) };
                *reinterpret_cast<s16x4*>(Qb + (size_t)p * HD + d0) = o4;
            }
        }
    } else if (s == 1) {
        short* Kb = Kp + bh * (size_t)(HW * HD);
        #pragma unroll
        for (int mi = 0; mi < 4; mi++) {
            int d0 = wm + mi * 16 + quad * 4;
            #pragma unroll
            for (int ni = 0; ni < 4; ni++) {
                int p = p0 + wn + ni * 16 + l16;
                const float4 eh = *reinterpret_cast<const float4*>(pos_h + (p >> 5) * HD + d0);
                const float4 ew = *reinterpret_cast<const float4*>(pos_w + (p & 31) * HD + d0);
                f32x4 a = acc[mi][ni];
                s16x4 o4 = { f2bf(a.x + eh.x + ew.x), f2bf(a.y + eh.y + ew.y),
                             f2bf(a.z + eh.z + ew.z), f2bf(a.w + eh.w + ew.w) };
                *reinterpret_cast<s16x4*>(Kb + (size_t)p * HD + d0) = o4;
            }
        }
    } else {
        __syncthreads();   // done with As/Bs before vb overlay
        #pragma unroll
        for (int mi = 0; mi < 4; mi++) {
            int d0 = wm + mi * 16 + quad * 4;
            #pragma unroll
            for (int ni = 0; ni < 4; ni++) {
                int p = wn + ni * 16 + l16;
                f32x4 a = acc[mi][ni];
                vb[(d0 + 0) * 136 + p] = f2bf(a.x);
                vb[(d0 + 1) * 136 + p] = f2bf(a.y);
                vb[(d0 + 2) * 136 + p] = f2bf(a.z);
                vb[(d0 + 3) * 136 + p] = f2bf(a.w);
            }
        }
        __syncthreads();
        short* Vb = Vt + bh * (size_t)(HD * HW);
        int d = tid >> 1, half = tid & 1;
        #pragma unroll
        for (int j = 0; j < 8; j++) {
            s16x8 v8 = *(const s16x8*)(vb + d * 136 + half * 64 + j * 8);
            *reinterpret_cast<s16x8*>(Vb + (size_t)d * HW + p0 + half * 64 + j * 8) = v8;
        }
    }
}

// ---------------------------------------------------------------------------
// Fused attention: 256 threads = 4 waves x 32 Q-ROWS, kt = 64 keys x 16 iters.
// R1 (re-run; prior bench was an infra failure, no data):
//  * K/V LDS DOUBLE-BUFFERED -> ONE barrier per kt-iter (was 2). Stage-writes
//    for tile kt+1 overlap other waves' MFMA on tile kt; global prefetch for
//    kt+2 stays in flight across a full compute phase.
//  * Ps shrunk 16KB->10KB: P handled in two 32-key halves through a padded
//    per-wave [32][40] strip (pad-40 rows spread banks; no XOR needed).
//    Total LDS 74KB -> 2 blocks/CU guaranteed (148KB <= 160KB).
//  * s_setprio(1) around MFMA clusters (T5).
// Grid 512 (bh = flat&63: XCD-affine), 2 blocks/CU.
// S^T = K.Q^T -> C rows = keys (4 consecutive per lane) -> packed s16x4
// P=exp2(S') writes; b128 read-back as A-frags; l via MFMA vs ones; O += P.V.
// ---------------------------------------------------------------------------
__global__ __launch_bounds__(256, 2) void attn_fused(
    const short* __restrict__ Q, const short* __restrict__ Kp,
    const short* __restrict__ Vt, float* __restrict__ out)
{
    __shared__ __align__(16) short Ks[2][64 * 128];   // [buf][key][d] swz: c^(key&15)
    __shared__ __align__(16) short Vs[2][128 * 64];   // [buf][d][key] swz: c^(d&7)
    __shared__ __align__(16) short Ps[4][32 * 40];    // per-wave [q][32keys], pad 40

    const int flat = blockIdx.x;
    const int qt = flat >> 6;              // 0..7
    const int bh = flat & 63;              // XCD-affine: bh%8 == blockIdx%8
    const int tid = threadIdx.x;
    const int wave = tid >> 6, lane = tid & 63;
    const int l16 = lane & 15, quad = lane >> 4;

    const short* Qb = Q + (size_t)bh * (HW * HD);
    const short* Kb = Kp + (size_t)bh * (HW * HD);
    const short* Vb = Vt + (size_t)bh * (HD * HW);
    short* myP = Ps[wave];

    const int q0 = qt * 128 + wave * 32;

    // Q fragments (B-operand for S^T): this wave's 32 rows, K=128 -> 2x4 frags
    s16x8 bQ[2][4];
    #pragma unroll
    for (int nt = 0; nt < 2; nt++)
        #pragma unroll
        for (int kk = 0; kk < 4; kk++)
            bQ[nt][kk] = *(const s16x8*)(Qb + (size_t)(q0 + nt * 16 + l16) * HD
                                         + kk * 32 + quad * 8);

    s16x8 ones;
    #pragma unroll
    for (int j = 0; j < 8; j++) ones[j] = (short)0x3F80;   // bf16 1.0

    f32x4 Oacc[2][8];
    #pragma unroll
    for (int mt = 0; mt < 2; mt++)
        #pragma unroll
        for (int dt = 0; dt < 8; dt++)
            Oacc[mt][dt] = f32x4{0.f, 0.f, 0.f, 0.f};
    f32x4 lacc[2] = { f32x4{0.f, 0.f, 0.f, 0.f}, f32x4{0.f, 0.f, 0.f, 0.f} };

    // staging geometry (256 thr, 4 chunks each per matrix; phys thread-const)
    const int kKey = tid >> 4, kC = tid & 15;          // K: 16 keys x 16 chunks
    const int kPhys = kC ^ kKey;                       // key&15 == kKey
    const short* kgp = Kb + (size_t)kKey * HD + kC * 8;
    const int kOff = kKey * 128 + kPhys * 8;
    const int vD = tid >> 3, vC = tid & 7;             // V: 32 d x 8 chunks
    const int vPhys = vC ^ (vD & 7);
    const short* vgp = Vb + (size_t)vD * HW + vC * 8;
    const int vOff = vD * 64 + vPhys * 8;

    s16x8 kreg[4], vreg[4];
    // tile 0 -> regs -> buf0
    #pragma unroll
    for (int i = 0; i < 4; i++) {
        kreg[i] = *(const s16x8*)(kgp + (size_t)(i * 16) * HD);
        vreg[i] = *(const s16x8*)(vgp + (size_t)(i * 32) * HW);
    }
    #pragma unroll
    for (int i = 0; i < 4; i++) {
        *(s16x8*)(&Ks[0][kOff] + i * 16 * 128) = kreg[i];
        *(s16x8*)(&Vs[0][vOff] + i * 32 * 64) = vreg[i];
    }
    // tile 1 -> regs
    #pragma unroll
    for (int i = 0; i < 4; i++) {
        kreg[i] = *(const s16x8*)(kgp + (size_t)(64 + i * 16) * HD);
        vreg[i] = *(const s16x8*)(vgp + 64 + (size_t)(i * 32) * HW);
    }
    __syncthreads();

    #pragma unroll 1
    for (int kt = 0; kt < 16; kt++) {
        const int cur = kt & 1, nxt = cur ^ 1;
        const short* ks = Ks[cur];
        const short* vs = Vs[cur];

        // commit tile kt+1 regs -> other buffer (overlaps compute of tile kt
        // in other waves; safe: nxt buffer last read in iter kt-1, barrier'd)
        #pragma unroll
        for (int i = 0; i < 4; i++) {
            *(s16x8*)(&Ks[nxt][kOff] + i * 16 * 128) = kreg[i];
            *(s16x8*)(&Vs[nxt][vOff] + i * 32 * 64) = vreg[i];
        }
        // prefetch tile kt+2 (wraps at end; harmless L2-hot reload)
        int ktn = (kt + 2) & 15;
        #pragma unroll
        for (int i = 0; i < 4; i++) {
            kreg[i] = *(const s16x8*)(kgp + (size_t)(ktn * 64 + i * 16) * HD);
            vreg[i] = *(const s16x8*)(vgp + ktn * 64 + (size_t)(i * 32) * HW);
        }

        // ---- S^T: 64 keys x 32 qrows (aK shared across both q-tiles)
        f32x4 c[4][2];
        __builtin_amdgcn_s_setprio(1);
        #pragma unroll
        for (int mtp = 0; mtp < 4; mtp++) {
            s16x8 aK[4];
            #pragma unroll
            for (int kk = 0; kk < 4; kk++)
                aK[kk] = *(const s16x8*)(ks + (mtp * 16 + l16) * 128
                                         + (((kk * 4 + quad) ^ l16) * 8));
            c[mtp][0] = f32x4{0.f, 0.f, 0.f, 0.f};
            c[mtp][1] = f32x4{0.f, 0.f, 0.f, 0.f};
            #pragma unroll
            for (int kk = 0; kk < 4; kk++) {
                c[mtp][0] = __builtin_amdgcn_mfma_f32_16x16x32_bf16(
                    aK[kk], bQ[0][kk], c[mtp][0], 0, 0, 0);
                c[mtp][1] = __builtin_amdgcn_mfma_f32_16x16x32_bf16(
                    aK[kk], bQ[1][kk], c[mtp][1], 0, 0, 0);
            }
        }
        __builtin_amdgcn_s_setprio(0);

        // ---- two 32-key halves: P pack -> strip -> aP -> l, O (in-wave DS
        //      ordering handles strip reuse across halves; no barrier)
        #pragma unroll
        for (int h = 0; h < 2; h++) {
            #pragma unroll
            for (int m2 = 0; m2 < 2; m2++)
                #pragma unroll
                for (int nt = 0; nt < 2; nt++) {
                    f32x4 pv = c[h * 2 + m2][nt];
                    s16x4 pp = { f2bf(__builtin_amdgcn_exp2f(pv[0])),
                                 f2bf(__builtin_amdgcn_exp2f(pv[1])),
                                 f2bf(__builtin_amdgcn_exp2f(pv[2])),
                                 f2bf(__builtin_amdgcn_exp2f(pv[3])) };
                    int q = nt * 16 + l16;
                    // local key = m2*16 + quad*4 (+reg), padded row of 40
                    *(s16x4*)(myP + q * 40 + m2 * 16 + quad * 4) = pp;
                }

            s16x8 aP[2];
            #pragma unroll
            for (int mt = 0; mt < 2; mt++)
                aP[mt] = *(const s16x8*)(myP + (mt * 16 + l16) * 40 + quad * 8);

            __builtin_amdgcn_s_setprio(1);
            #pragma unroll
            for (int mt = 0; mt < 2; mt++)
                lacc[mt] = __builtin_amdgcn_mfma_f32_16x16x32_bf16(
                    aP[mt], ones, lacc[mt], 0, 0, 0);

            #pragma unroll
            for (int dt = 0; dt < 8; dt++) {
                s16x8 bV = *(const s16x8*)(vs + (dt * 16 + l16) * 64
                                           + (((h * 4 + quad) ^ (l16 & 7)) * 8));
                #pragma unroll
                for (int mt = 0; mt < 2; mt++)
                    Oacc[mt][dt] = __builtin_amdgcn_mfma_f32_16x16x32_bf16(
                        aP[mt], bV, Oacc[mt][dt], 0, 0, 0);
            }
            __builtin_amdgcn_s_setprio(0);
        }
        __syncthreads();   // single barrier per iter: frees nxt for kt+1
    }

    // epilogue: O/l, stored transposed -> out[b][h][d][p] FP32
    float* ob = out + (size_t)bh * (HD * HW);
    #pragma unroll
    for (int mt = 0; mt < 2; mt++) {
        float inv[4];
        #pragma unroll
        for (int r = 0; r < 4; r++) inv[r] = __builtin_amdgcn_rcpf(lacc[mt][r]);
        int prow = q0 + mt * 16 + quad * 4;
        #pragma unroll
        for (int dt = 0; dt < 8; dt++) {
            int d = dt * 16 + l16;
            f32x4 o = Oacc[mt][dt];
            float4 o4 = { o[0] * inv[0], o[1] * inv[1],
                          o[2] * inv[2], o[3] * inv[3] };
            *reinterpret_cast<float4*>(ob + (size_t)d * HW + prow) = o4;
        }
    }
}

// ---------------------------------------------------------------------------
extern "C" void kernel_launch(void* const* d_in, const int* in_sizes, int n_in,
                              void* d_out, int out_size, void* d_ws, size_t ws_size,
                              hipStream_t stream) {
    const float* x  = (const float*)d_in[0];
    const float* w  = (const float*)d_in[1];
    const float* ph = (const float*)d_in[2];
    const float* pw = (const float*)d_in[3];

    const size_t BHPD = (size_t)NB * NH * HW * HD;   // 8,388,608 elems
    short* Q    = (short*)d_ws;
    short* Kp   = Q + BHPD;
    short* Vt   = Kp + BHPD;
    short* xT   = Vt + BHPD;
    short* Wb   = xT + (size_t)NB * HW * CIN;
    float* outp = (float*)d_out;

    prep_xw<<<dim3(NB * 16 * 32 + 768), 256, 0, stream>>>(x, w, xT, Wb);
    qkv_proj<<<dim3(8, 12, NB), 256, 0, stream>>>(xT, Wb, ph, pw, Q, Kp, Vt);
    attn_fused<<<dim3(512), 256, 0, stream>>>(Q, Kp, Vt, outp);
}

// Round 3
// 167.004 us; speedup vs baseline: 1.0510x; 1.0510x over previous
//
#include <hip/hip_runtime.h>

#define NB 16
#define NH 4
#define HD 128
#define HW 1024
#define CIN 512

typedef short s16x8 __attribute__((ext_vector_type(8)));
typedef short s16x4 __attribute__((ext_vector_type(4)));
typedef float f32x4 __attribute__((ext_vector_type(4)));

static __device__ __forceinline__ short f2bf(float f) {
    union { float f; unsigned u; } v; v.f = f;
    unsigned r = v.u + 0x7fffu + ((v.u >> 16) & 1u);   // round-to-nearest-even
    return (short)(r >> 16);
}

// ---------------------------------------------------------------------------
// prep: x[b][c][p] fp32 -> xT[b][p][c] bf16 (32x32 LDS tile transpose)
//       W[o][c]   fp32 -> Wb bf16 (elementwise)
// ---------------------------------------------------------------------------
__global__ __launch_bounds__(256) void prep_xw(
    const float* __restrict__ x, const float* __restrict__ w,
    short* __restrict__ xT, short* __restrict__ Wb)
{
    int blk = blockIdx.x;
    if (blk < NB * 16 * 32) {                  // 8192 transpose tiles
        int b = blk >> 9, rem = blk & 511;
        int ct = rem >> 5, pt = rem & 31;      // 16 c-tiles x 32 p-tiles
        __shared__ float tile[32][33];
        int tc = threadIdx.x >> 5;             // 0..7
        int tp = threadIdx.x & 31;             // 0..31
        const float* xb = x + ((size_t)b * CIN + ct * 32) * HW + pt * 32;
        #pragma unroll
        for (int i = 0; i < 4; i++)
            tile[tc + i * 8][tp] = xb[(size_t)(tc + i * 8) * HW + tp];
        __syncthreads();
        int p = threadIdx.x >> 3, cq = threadIdx.x & 7;
        short* xo = xT + ((size_t)b * HW + pt * 32 + p) * CIN + ct * 32 + cq * 4;
        s16x4 o4 = { f2bf(tile[cq * 4 + 0][p]), f2bf(tile[cq * 4 + 1][p]),
                     f2bf(tile[cq * 4 + 2][p]), f2bf(tile[cq * 4 + 3][p]) };
        *reinterpret_cast<s16x4*>(xo) = o4;
    } else {
        int wb = blk - NB * 16 * 32;           // 0..767, 1024 elems each
        size_t base = (size_t)wb * 1024 + threadIdx.x * 4;
        const float4 v = *reinterpret_cast<const float4*>(w + base);
        s16x4 o4 = { f2bf(v.x), f2bf(v.y), f2bf(v.z), f2bf(v.w) };
        *reinterpret_cast<s16x4*>(Wb + base) = o4;
    }
}

// ---------------------------------------------------------------------------
// qkv projection GEMM, BK=64, reg-prefetch pipelined. LDS [128][64] unpadded
// + 16B-chunk XOR swizzle (phys = c ^ (row&7)): every b128 access 2-way (free).
//   s=0: Q = val * (128^-0.5 * log2e)   [p][d]
//   s=1: K' = val + pos_h + pos_w       [p][d]
//   s=2: Vt = val                       [d][p]  -- p PERMUTED within 32-groups
//        (slot = 8*qs + 4*t + r  <-  u = 16*t + 4*qs + r), so attn's PV can
//        consume P directly from the S^T C-layout registers (no LDS trip).
// ---------------------------------------------------------------------------
__global__ __launch_bounds__(256, 3) void qkv_proj(
    const short* __restrict__ xT, const short* __restrict__ Wb,
    const float* __restrict__ pos_h, const float* __restrict__ pos_w,
    short* __restrict__ Q, short* __restrict__ Kp, short* __restrict__ Vt)
{
    __shared__ __align__(16) char smem[34816];
    short* As = (short*)smem;               // [128][64] swizzled
    short* Bs = As + 128 * 64;              // [128][64] swizzled
    short* vb = (short*)smem;               // [128][136] reused for V epilogue

    const int pt = blockIdx.x, ot = blockIdx.y, b = blockIdx.z;
    const int tid = threadIdx.x;
    const int wave = tid >> 6, lane = tid & 63;
    const int l16 = lane & 15, quad = lane >> 4;
    const int wm = (wave & 1) * 64, wn = (wave >> 1) * 64;
    const int o0 = ot * 128, p0 = pt * 128;

    const short* xb = xT + (size_t)b * HW * CIN;

    // staging: thread handles rows p*32 + r0 (p<4), chunk c0; row&7 = r0&7 const
    const int r0 = tid >> 3, c0 = tid & 7;
    const int sphys = c0 ^ (r0 & 7);
    const short* wp = Wb + (size_t)(o0 + r0) * CIN + c0 * 8;
    const short* xp = xb + (size_t)(p0 + r0) * CIN + c0 * 8;
    short* adst = As + r0 * 64 + sphys * 8;
    short* bdst = Bs + r0 * 64 + sphys * 8;

    f32x4 acc[4][4];
    #pragma unroll
    for (int i = 0; i < 4; i++)
        #pragma unroll
        for (int j = 0; j < 4; j++)
            acc[i][j] = f32x4{0.f, 0.f, 0.f, 0.f};

    s16x8 wreg[4], xreg[4];
    #pragma unroll
    for (int p = 0; p < 4; p++) {
        wreg[p] = *(const s16x8*)(wp + (size_t)(p * 32) * CIN);
        xreg[p] = *(const s16x8*)(xp + (size_t)(p * 32) * CIN);
    }

    #pragma unroll 1
    for (int kc = 0; kc < CIN; kc += 64) {
        #pragma unroll
        for (int p = 0; p < 4; p++) {
            *(s16x8*)(adst + p * 32 * 64) = wreg[p];
            *(s16x8*)(bdst + p * 32 * 64) = xreg[p];
        }
        __syncthreads();
        int kcn = (kc + 64) & (CIN - 1);       // wrap: last prefetch harmless
        #pragma unroll
        for (int p = 0; p < 4; p++) {
            wreg[p] = *(const s16x8*)(wp + kcn + (size_t)(p * 32) * CIN);
            xreg[p] = *(const s16x8*)(xp + kcn + (size_t)(p * 32) * CIN);
        }
        #pragma unroll
        for (int kk = 0; kk < 2; kk++) {
            s16x8 aF[4], bF[4];
            #pragma unroll
            for (int mi = 0; mi < 4; mi++)
                aF[mi] = *(const s16x8*)(As + (wm + mi * 16 + l16) * 64
                                         + (((kk * 4 + quad) ^ (l16 & 7)) * 8));
            #pragma unroll
            for (int ni = 0; ni < 4; ni++)
                bF[ni] = *(const s16x8*)(Bs + (wn + ni * 16 + l16) * 64
                                         + (((kk * 4 + quad) ^ (l16 & 7)) * 8));
            #pragma unroll
            for (int mi = 0; mi < 4; mi++)
                #pragma unroll
                for (int ni = 0; ni < 4; ni++)
                    acc[mi][ni] = __builtin_amdgcn_mfma_f32_16x16x32_bf16(
                        aF[mi], bF[ni], acc[mi][ni], 0, 0, 0);
        }
        __syncthreads();
    }

    const int s = ot >> 2, h = ot & 3;
    const size_t bh = (size_t)(b * NH + h);

    if (s == 0) {
        const float qs = 0.08838834764831845f * 1.4426950408889634f; // scale*log2e
        short* Qb = Q + bh * (size_t)(HW * HD);
        #pragma unroll
        for (int mi = 0; mi < 4; mi++) {
            int d0 = wm + mi * 16 + quad * 4;
            #pragma unroll
            for (int ni = 0; ni < 4; ni++) {
                int p = p0 + wn + ni * 16 + l16;
                f32x4 a = acc[mi][ni];
                s16x4 o4 = { f2bf(a.x * qs), f2bf(a.y * qs),
                             f2bf(a.z * qs), f2bf(a.w * qs) };
                *reinterpret_cast<s16x4*>(Qb + (size_t)p * HD + d0) = o4;
            }
        }
    } else if (s == 1) {
        short* Kb = Kp + bh * (size_t)(HW * HD);
        #pragma unroll
        for (int mi = 0; mi < 4; mi++) {
            int d0 = wm + mi * 16 + quad * 4;
            #pragma unroll
            for (int ni = 0; ni < 4; ni++) {
                int p = p0 + wn + ni * 16 + l16;
                const float4 eh = *reinterpret_cast<const float4*>(pos_h + (p >> 5) * HD + d0);
                const float4 ew = *reinterpret_cast<const float4*>(pos_w + (p & 31) * HD + d0);
                f32x4 a = acc[mi][ni];
                s16x4 o4 = { f2bf(a.x + eh.x + ew.x), f2bf(a.y + eh.y + ew.y),
                             f2bf(a.z + eh.z + ew.z), f2bf(a.w + eh.w + ew.w) };
                *reinterpret_cast<s16x4*>(Kb + (size_t)p * HD + d0) = o4;
            }
        }
    } else {
        __syncthreads();   // done with As/Bs before vb overlay
        #pragma unroll
        for (int mi = 0; mi < 4; mi++) {
            int d0 = wm + mi * 16 + quad * 4;
            #pragma unroll
            for (int ni = 0; ni < 4; ni++) {
                int p = wn + ni * 16 + l16;
                f32x4 a = acc[mi][ni];
                vb[(d0 + 0) * 136 + p] = f2bf(a.x);
                vb[(d0 + 1) * 136 + p] = f2bf(a.y);
                vb[(d0 + 2) * 136 + p] = f2bf(a.z);
                vb[(d0 + 3) * 136 + p] = f2bf(a.w);
            }
        }
        __syncthreads();
        short* Vb = Vt + bh * (size_t)(HD * HW);
        int d = tid >> 1, half = tid & 1;
        // key-permuted store: out slot group g=(half*2+(j>>2)), qs=(j&3):
        //   slots 8qs..8qs+3 (t=0) <- u = g*32 + 4qs + r
        //   slots 8qs+4..+7 (t=1) <- u = g*32 + 16 + 4qs + r
        #pragma unroll
        for (int j = 0; j < 8; j++) {
            const short* row = vb + d * 136;
            int base = (half * 2 + (j >> 2)) * 32 + (j & 3) * 4;
            s16x4 lo = *(const s16x4*)(row + base);
            s16x4 hi = *(const s16x4*)(row + base + 16);
            s16x8 v8 = { lo[0], lo[1], lo[2], lo[3],
                         hi[0], hi[1], hi[2], hi[3] };
            *reinterpret_cast<s16x8*>(Vb + (size_t)d * HW + p0 + half * 64 + j * 8) = v8;
        }
    }
}

// ---------------------------------------------------------------------------
// Fused attention: 256 threads = 4 waves x 32 Q-ROWS, kt = 64 keys x 16 iters.
// R3: P NEVER TOUCHES LDS. V was stored key-PERMUTED (see qkv_proj), chosen so
// that the 8 keys each lane holds in S^T's C-layout regs (c[2h][mt].r ->
// key 32h+quad*4+r, c[2h+1][mt].r -> key 32h+16+quad*4+r) are exactly the
// A-frag k-slots quad*8+j it needs for PV. exp2+pack in registers -> MFMA.
// Removes 8 b64 writes + 4 b128 reads per wave-iter (-17% LDS traffic), the
// 2x ~150cy LDS write->read latency on the critical path, and the Ps buffer.
// K/V LDS double-buffered, ONE barrier per kt-iter; s_setprio around MFMA.
// Grid 512 (bh = flat&63: XCD-affine), 2 blocks/CU (66KB LDS).
// ---------------------------------------------------------------------------
__global__ __launch_bounds__(256, 2) void attn_fused(
    const short* __restrict__ Q, const short* __restrict__ Kp,
    const short* __restrict__ Vt, float* __restrict__ out)
{
    __shared__ __align__(16) short Ks[2][64 * 128];   // [buf][key][d] swz: c^(key&15)
    __shared__ __align__(16) short Vs[2][128 * 64];   // [buf][d][slot] swz: c^(d&7)

    const int flat = blockIdx.x;
    const int qt = flat >> 6;              // 0..7
    const int bh = flat & 63;              // XCD-affine: bh%8 == blockIdx%8
    const int tid = threadIdx.x;
    const int wave = tid >> 6, lane = tid & 63;
    const int l16 = lane & 15, quad = lane >> 4;

    const short* Qb = Q + (size_t)bh * (HW * HD);
    const short* Kb = Kp + (size_t)bh * (HW * HD);
    const short* Vb = Vt + (size_t)bh * (HD * HW);

    const int q0 = qt * 128 + wave * 32;

    // Q fragments (B-operand for S^T): this wave's 32 rows, K=128 -> 2x4 frags
    s16x8 bQ[2][4];
    #pragma unroll
    for (int nt = 0; nt < 2; nt++)
        #pragma unroll
        for (int kk = 0; kk < 4; kk++)
            bQ[nt][kk] = *(const s16x8*)(Qb + (size_t)(q0 + nt * 16 + l16) * HD
                                         + kk * 32 + quad * 8);

    s16x8 ones;
    #pragma unroll
    for (int j = 0; j < 8; j++) ones[j] = (short)0x3F80;   // bf16 1.0

    f32x4 Oacc[2][8];
    #pragma unroll
    for (int mt = 0; mt < 2; mt++)
        #pragma unroll
        for (int dt = 0; dt < 8; dt++)
            Oacc[mt][dt] = f32x4{0.f, 0.f, 0.f, 0.f};
    f32x4 lacc[2] = { f32x4{0.f, 0.f, 0.f, 0.f}, f32x4{0.f, 0.f, 0.f, 0.f} };

    // staging geometry (256 thr, 4 chunks each per matrix; phys thread-const)
    const int kKey = tid >> 4, kC = tid & 15;          // K: 16 keys x 16 chunks
    const int kPhys = kC ^ kKey;                       // key&15 == kKey
    const short* kgp = Kb + (size_t)kKey * HD + kC * 8;
    const int kOff = kKey * 128 + kPhys * 8;
    const int vD = tid >> 3, vC = tid & 7;             // V: 32 d x 8 chunks
    const int vPhys = vC ^ (vD & 7);
    const short* vgp = Vb + (size_t)vD * HW + vC * 8;
    const int vOff = vD * 64 + vPhys * 8;

    s16x8 kreg[4], vreg[4];
    // tile 0 -> regs -> buf0
    #pragma unroll
    for (int i = 0; i < 4; i++) {
        kreg[i] = *(const s16x8*)(kgp + (size_t)(i * 16) * HD);
        vreg[i] = *(const s16x8*)(vgp + (size_t)(i * 32) * HW);
    }
    #pragma unroll
    for (int i = 0; i < 4; i++) {
        *(s16x8*)(&Ks[0][kOff] + i * 16 * 128) = kreg[i];
        *(s16x8*)(&Vs[0][vOff] + i * 32 * 64) = vreg[i];
    }
    // tile 1 -> regs
    #pragma unroll
    for (int i = 0; i < 4; i++) {
        kreg[i] = *(const s16x8*)(kgp + (size_t)(64 + i * 16) * HD);
        vreg[i] = *(const s16x8*)(vgp + 64 + (size_t)(i * 32) * HW);
    }
    __syncthreads();

    #pragma unroll 1
    for (int kt = 0; kt < 16; kt++) {
        const int cur = kt & 1, nxt = cur ^ 1;
        const short* ks = Ks[cur];
        const short* vs = Vs[cur];

        // commit tile kt+1 regs -> other buffer (overlaps compute of tile kt
        // in other waves; safe: nxt buffer last read in iter kt-1, barrier'd)
        #pragma unroll
        for (int i = 0; i < 4; i++) {
            *(s16x8*)(&Ks[nxt][kOff] + i * 16 * 128) = kreg[i];
            *(s16x8*)(&Vs[nxt][vOff] + i * 32 * 64) = vreg[i];
        }
        // prefetch tile kt+2 (wraps at end; harmless L2-hot reload)
        int ktn = (kt + 2) & 15;
        #pragma unroll
        for (int i = 0; i < 4; i++) {
            kreg[i] = *(const s16x8*)(kgp + (size_t)(ktn * 64 + i * 16) * HD);
            vreg[i] = *(const s16x8*)(vgp + ktn * 64 + (size_t)(i * 32) * HW);
        }

        // ---- S^T: 64 keys x 32 qrows (aK shared across both q-tiles)
        f32x4 c[4][2];
        __builtin_amdgcn_s_setprio(1);
        #pragma unroll
        for (int mtp = 0; mtp < 4; mtp++) {
            s16x8 aK[4];
            #pragma unroll
            for (int kk = 0; kk < 4; kk++)
                aK[kk] = *(const s16x8*)(ks + (mtp * 16 + l16) * 128
                                         + (((kk * 4 + quad) ^ l16) * 8));
            c[mtp][0] = f32x4{0.f, 0.f, 0.f, 0.f};
            c[mtp][1] = f32x4{0.f, 0.f, 0.f, 0.f};
            #pragma unroll
            for (int kk = 0; kk < 4; kk++) {
                c[mtp][0] = __builtin_amdgcn_mfma_f32_16x16x32_bf16(
                    aK[kk], bQ[0][kk], c[mtp][0], 0, 0, 0);
                c[mtp][1] = __builtin_amdgcn_mfma_f32_16x16x32_bf16(
                    aK[kk], bQ[1][kk], c[mtp][1], 0, 0, 0);
            }
        }
        __builtin_amdgcn_s_setprio(0);

        // ---- P = exp2(S') packed ENTIRELY in registers (V rows permuted to
        //      match the C-layout keys each lane holds). Two 32-key halves.
        #pragma unroll
        for (int h = 0; h < 2; h++) {
            s16x8 aP[2];
            #pragma unroll
            for (int mt = 0; mt < 2; mt++) {
                f32x4 e0 = c[2 * h][mt], e1 = c[2 * h + 1][mt];
                aP[mt] = s16x8{
                    f2bf(__builtin_amdgcn_exp2f(e0[0])),
                    f2bf(__builtin_amdgcn_exp2f(e0[1])),
                    f2bf(__builtin_amdgcn_exp2f(e0[2])),
                    f2bf(__builtin_amdgcn_exp2f(e0[3])),
                    f2bf(__builtin_amdgcn_exp2f(e1[0])),
                    f2bf(__builtin_amdgcn_exp2f(e1[1])),
                    f2bf(__builtin_amdgcn_exp2f(e1[2])),
                    f2bf(__builtin_amdgcn_exp2f(e1[3])) };
            }

            __builtin_amdgcn_s_setprio(1);
            #pragma unroll
            for (int mt = 0; mt < 2; mt++)
                lacc[mt] = __builtin_amdgcn_mfma_f32_16x16x32_bf16(
                    aP[mt], ones, lacc[mt], 0, 0, 0);

            #pragma unroll
            for (int dt = 0; dt < 8; dt++) {
                s16x8 bV = *(const s16x8*)(vs + (dt * 16 + l16) * 64
                                           + (((h * 4 + quad) ^ (l16 & 7)) * 8));
                #pragma unroll
                for (int mt = 0; mt < 2; mt++)
                    Oacc[mt][dt] = __builtin_amdgcn_mfma_f32_16x16x32_bf16(
                        aP[mt], bV, Oacc[mt][dt], 0, 0, 0);
            }
            __builtin_amdgcn_s_setprio(0);
        }
        __syncthreads();   // single barrier per iter: frees nxt for kt+1
    }

    // epilogue: O/l, stored transposed -> out[b][h][d][p] FP32
    float* ob = out + (size_t)bh * (HD * HW);
    #pragma unroll
    for (int mt = 0; mt < 2; mt++) {
        float inv[4];
        #pragma unroll
        for (int r = 0; r < 4; r++) inv[r] = __builtin_amdgcn_rcpf(lacc[mt][r]);
        int prow = q0 + mt * 16 + quad * 4;
        #pragma unroll
        for (int dt = 0; dt < 8; dt++) {
            int d = dt * 16 + l16;
            f32x4 o = Oacc[mt][dt];
            float4 o4 = { o[0] * inv[0], o[1] * inv[1],
                          o[2] * inv[2], o[3] * inv[3] };
            *reinterpret_cast<float4*>(ob + (size_t)d * HW + prow) = o4;
        }
    }
}

// ---------------------------------------------------------------------------
extern "C" void kernel_launch(void* const* d_in, const int* in_sizes, int n_in,
                              void* d_out, int out_size, void* d_ws, size_t ws_size,
                              hipStream_t stream) {
    const float* x  = (const float*)d_in[0];
    const float* w  = (const float*)d_in[1];
    const float* ph = (const float*)d_in[2];
    const float* pw = (const float*)d_in[3];

    const size_t BHPD = (size_t)NB * NH * HW * HD;   // 8,388,608 elems
    short* Q    = (short*)d_ws;
    short* Kp   = Q + BHPD;
    short* Vt   = Kp + BHPD;
    short* xT   = Vt + BHPD;
    short* Wb   = xT + (size_t)NB * HW * CIN;
    float* outp = (float*)d_out;

    prep_xw<<<dim3(NB * 16 * 32 + 768), 256, 0, stream>>>(x, w, xT, Wb);
    qkv_proj<<<dim3(8, 12, NB), 256, 0, stream>>>(xT, Wb, ph, pw, Q, Kp, Vt);
    attn_fused<<<dim3(512), 256, 0, stream>>>(Q, Kp, Vt, outp);
}

// Round 4
// 164.170 us; speedup vs baseline: 1.0692x; 1.0173x over previous
//
#include <hip/hip_runtime.h>

#define NB 16
#define NH 4
#define HD 128
#define HW 1024
#define CIN 512

typedef short s16x8 __attribute__((ext_vector_type(8)));
typedef short s16x4 __attribute__((ext_vector_type(4)));
typedef float f32x4 __attribute__((ext_vector_type(4)));

static __device__ __forceinline__ short f2bf(float f) {
    union { float f; unsigned u; } v; v.f = f;
    unsigned r = v.u + 0x7fffu + ((v.u >> 16) & 1u);   // round-to-nearest-even
    return (short)(r >> 16);
}

// async global->LDS DMA, 16B per lane. LDS dest is wave-uniform base + lane*16
// (linear); global src is per-lane (carries the XOR swizzle).
static __device__ __forceinline__ void gload16(const short* g, short* l) {
    __builtin_amdgcn_global_load_lds(
        (const __attribute__((address_space(1))) unsigned int*)g,
        (__attribute__((address_space(3))) unsigned int*)l, 16, 0, 0);
}

// ---------------------------------------------------------------------------
// prep: x[b][c][p] fp32 -> xT[b][p][c] bf16 (32x32 LDS tile transpose)
//       W[o][c]   fp32 -> Wb bf16 (elementwise)
// ---------------------------------------------------------------------------
__global__ __launch_bounds__(256) void prep_xw(
    const float* __restrict__ x, const float* __restrict__ w,
    short* __restrict__ xT, short* __restrict__ Wb)
{
    int blk = blockIdx.x;
    if (blk < NB * 16 * 32) {                  // 8192 transpose tiles
        int b = blk >> 9, rem = blk & 511;
        int ct = rem >> 5, pt = rem & 31;      // 16 c-tiles x 32 p-tiles
        __shared__ float tile[32][33];
        int tc = threadIdx.x >> 5;             // 0..7
        int tp = threadIdx.x & 31;             // 0..31
        const float* xb = x + ((size_t)b * CIN + ct * 32) * HW + pt * 32;
        #pragma unroll
        for (int i = 0; i < 4; i++)
            tile[tc + i * 8][tp] = xb[(size_t)(tc + i * 8) * HW + tp];
        __syncthreads();
        int p = threadIdx.x >> 3, cq = threadIdx.x & 7;
        short* xo = xT + ((size_t)b * HW + pt * 32 + p) * CIN + ct * 32 + cq * 4;
        s16x4 o4 = { f2bf(tile[cq * 4 + 0][p]), f2bf(tile[cq * 4 + 1][p]),
                     f2bf(tile[cq * 4 + 2][p]), f2bf(tile[cq * 4 + 3][p]) };
        *reinterpret_cast<s16x4*>(xo) = o4;
    } else {
        int wb = blk - NB * 16 * 32;           // 0..767, 1024 elems each
        size_t base = (size_t)wb * 1024 + threadIdx.x * 4;
        const float4 v = *reinterpret_cast<const float4*>(w + base);
        s16x4 o4 = { f2bf(v.x), f2bf(v.y), f2bf(v.z), f2bf(v.w) };
        *reinterpret_cast<s16x4*>(Wb + base) = o4;
    }
}

// ---------------------------------------------------------------------------
// qkv projection GEMM, BK=64, m97 structure: global_load_lds DMA staging
// (width 16), single-buffered LDS, 2 barriers per K-step. Content keeps the
// 16B-chunk XOR swizzle (phys = c ^ (row&7)) via PRE-SWIZZLED per-lane global
// source + linear LDS dest (m173 pattern) -> frag reads & epilogues unchanged.
//   s=0: Q = val * (128^-0.5 * log2e)   [p][d]
//   s=1: K' = val + pos_h + pos_w       [p][d]
//   s=2: Vt = val                       [d][p]  -- p PERMUTED within 32-groups
//        (slot = 8*qs + 4*t + r  <-  u = 16*t + 4*qs + r), so attn's PV can
//        consume P directly from the S^T C-layout registers (no LDS trip).
// ---------------------------------------------------------------------------
__global__ __launch_bounds__(256, 3) void qkv_proj(
    const short* __restrict__ xT, const short* __restrict__ Wb,
    const float* __restrict__ pos_h, const float* __restrict__ pos_w,
    short* __restrict__ Q, short* __restrict__ Kp, short* __restrict__ Vt)
{
    __shared__ __align__(1024) char smem[34816];
    short* As = (short*)smem;               // [128][64] content-swizzled
    short* Bs = As + 128 * 64;              // [128][64] content-swizzled
    short* vb = (short*)smem;               // [128][136] reused for V epilogue

    const int pt = blockIdx.x, ot = blockIdx.y, b = blockIdx.z;
    const int tid = threadIdx.x;
    const int wave = tid >> 6, lane = tid & 63;
    const int l16 = lane & 15, quad = lane >> 4;
    const int wm = (wave & 1) * 64, wn = (wave >> 1) * 64;
    const int o0 = ot * 128, p0 = pt * 128;

    const short* xb = xT + (size_t)b * HW * CIN;

    // DMA staging geometry: wave w covers rows [w*32, w*32+32); instr j covers
    // 8 rows (1024 B). Lane: row_local = j*8 + (lane>>3), phys chunk = lane&7.
    // Source chunk = phys ^ (row&7); row&7 == lane>>3 (j*8, w*32 are 0 mod 8).
    const int r8 = lane >> 3, c8 = lane & 7;
    const int sch = c8 ^ r8;                  // pre-swizzled source chunk
    const short* wsrc = Wb + (size_t)(o0 + wave * 32 + r8) * CIN + sch * 8;
    const short* xsrc = xb + (size_t)(p0 + wave * 32 + r8) * CIN + sch * 8;
    short* adst = As + wave * 2048;           // + j*512 shorts (= j*1024 B)
    short* bdst = Bs + wave * 2048;

    f32x4 acc[4][4];
    #pragma unroll
    for (int i = 0; i < 4; i++)
        #pragma unroll
        for (int j = 0; j < 4; j++)
            acc[i][j] = f32x4{0.f, 0.f, 0.f, 0.f};

    #pragma unroll 1
    for (int kc = 0; kc < CIN; kc += 64) {
        #pragma unroll
        for (int j = 0; j < 4; j++) {
            gload16(wsrc + kc + (size_t)(j * 8) * CIN, adst + j * 512);
            gload16(xsrc + kc + (size_t)(j * 8) * CIN, bdst + j * 512);
        }
        __syncthreads();   // compiler drains vmcnt(0) before barrier
        #pragma unroll
        for (int kk = 0; kk < 2; kk++) {
            s16x8 aF[4], bF[4];
            #pragma unroll
            for (int mi = 0; mi < 4; mi++)
                aF[mi] = *(const s16x8*)(As + (wm + mi * 16 + l16) * 64
                                         + (((kk * 4 + quad) ^ (l16 & 7)) * 8));
            #pragma unroll
            for (int ni = 0; ni < 4; ni++)
                bF[ni] = *(const s16x8*)(Bs + (wn + ni * 16 + l16) * 64
                                         + (((kk * 4 + quad) ^ (l16 & 7)) * 8));
            #pragma unroll
            for (int mi = 0; mi < 4; mi++)
                #pragma unroll
                for (int ni = 0; ni < 4; ni++)
                    acc[mi][ni] = __builtin_amdgcn_mfma_f32_16x16x32_bf16(
                        aF[mi], bF[ni], acc[mi][ni], 0, 0, 0);
        }
        __syncthreads();   // all reads done before next DMA overwrites
    }

    const int s = ot >> 2, h = ot & 3;
    const size_t bh = (size_t)(b * NH + h);

    if (s == 0) {
        const float qs = 0.08838834764831845f * 1.4426950408889634f; // scale*log2e
        short* Qb = Q + bh * (size_t)(HW * HD);
        #pragma unroll
        for (int mi = 0; mi < 4; mi++) {
            int d0 = wm + mi * 16 + quad * 4;
            #pragma unroll
            for (int ni = 0; ni < 4; ni++) {
                int p = p0 + wn + ni * 16 + l16;
                f32x4 a = acc[mi][ni];
                s16x4 o4 = { f2bf(a.x * qs), f2bf(a.y * qs),
                             f2bf(a.z * qs), f2bf(a.w * qs) };
                *reinterpret_cast<s16x4*>(Qb + (size_t)p * HD + d0) = o4;
            }
        }
    } else if (s == 1) {
        short* Kb = Kp + bh * (size_t)(HW * HD);
        #pragma unroll
        for (int mi = 0; mi < 4; mi++) {
            int d0 = wm + mi * 16 + quad * 4;
            #pragma unroll
            for (int ni = 0; ni < 4; ni++) {
                int p = p0 + wn + ni * 16 + l16;
                const float4 eh = *reinterpret_cast<const float4*>(pos_h + (p >> 5) * HD + d0);
                const float4 ew = *reinterpret_cast<const float4*>(pos_w + (p & 31) * HD + d0);
                f32x4 a = acc[mi][ni];
                s16x4 o4 = { f2bf(a.x + eh.x + ew.x), f2bf(a.y + eh.y + ew.y),
                             f2bf(a.z + eh.z + ew.z), f2bf(a.w + eh.w + ew.w) };
                *reinterpret_cast<s16x4*>(Kb + (size_t)p * HD + d0) = o4;
            }
        }
    } else {
        __syncthreads();   // done with As/Bs before vb overlay
        #pragma unroll
        for (int mi = 0; mi < 4; mi++) {
            int d0 = wm + mi * 16 + quad * 4;
            #pragma unroll
            for (int ni = 0; ni < 4; ni++) {
                int p = wn + ni * 16 + l16;
                f32x4 a = acc[mi][ni];
                vb[(d0 + 0) * 136 + p] = f2bf(a.x);
                vb[(d0 + 1) * 136 + p] = f2bf(a.y);
                vb[(d0 + 2) * 136 + p] = f2bf(a.z);
                vb[(d0 + 3) * 136 + p] = f2bf(a.w);
            }
        }
        __syncthreads();
        short* Vb = Vt + bh * (size_t)(HD * HW);
        int d = tid >> 1, half = tid & 1;
        // key-permuted store: out slot group g=(half*2+(j>>2)), qs=(j&3):
        //   slots 8qs..8qs+3 (t=0) <- u = g*32 + 4qs + r
        //   slots 8qs+4..+7 (t=1) <- u = g*32 + 16 + 4qs + r
        #pragma unroll
        for (int j = 0; j < 8; j++) {
            const short* row = vb + d * 136;
            int base = (half * 2 + (j >> 2)) * 32 + (j & 3) * 4;
            s16x4 lo = *(const s16x4*)(row + base);
            s16x4 hi = *(const s16x4*)(row + base + 16);
            s16x8 v8 = { lo[0], lo[1], lo[2], lo[3],
                         hi[0], hi[1], hi[2], hi[3] };
            *reinterpret_cast<s16x8*>(Vb + (size_t)d * HW + p0 + half * 64 + j * 8) = v8;
        }
    }
}

// ---------------------------------------------------------------------------
// Fused attention: 256 threads = 4 waves x 32 Q-ROWS, kt = 64 keys x 16 iters.
// P NEVER TOUCHES LDS (R3, verified: bank conflicts = 0). V stored key-
// PERMUTED (see qkv_proj) so the 8 keys each lane holds in S^T's C-layout
// regs are exactly the A-frag k-slots it needs for PV; exp2+pack in regs.
// K/V LDS double-buffered, ONE barrier per kt-iter; s_setprio around MFMA.
// Grid 512 (bh = flat&63: XCD-affine), 2 blocks/CU (66KB LDS).
// ---------------------------------------------------------------------------
__global__ __launch_bounds__(256, 2) void attn_fused(
    const short* __restrict__ Q, const short* __restrict__ Kp,
    const short* __restrict__ Vt, float* __restrict__ out)
{
    __shared__ __align__(16) short Ks[2][64 * 128];   // [buf][key][d] swz: c^(key&15)
    __shared__ __align__(16) short Vs[2][128 * 64];   // [buf][d][slot] swz: c^(d&7)

    const int flat = blockIdx.x;
    const int qt = flat >> 6;              // 0..7
    const int bh = flat & 63;              // XCD-affine: bh%8 == blockIdx%8
    const int tid = threadIdx.x;
    const int wave = tid >> 6, lane = tid & 63;
    const int l16 = lane & 15, quad = lane >> 4;

    const short* Qb = Q + (size_t)bh * (HW * HD);
    const short* Kb = Kp + (size_t)bh * (HW * HD);
    const short* Vb = Vt + (size_t)bh * (HD * HW);

    const int q0 = qt * 128 + wave * 32;

    // Q fragments (B-operand for S^T): this wave's 32 rows, K=128 -> 2x4 frags
    s16x8 bQ[2][4];
    #pragma unroll
    for (int nt = 0; nt < 2; nt++)
        #pragma unroll
        for (int kk = 0; kk < 4; kk++)
            bQ[nt][kk] = *(const s16x8*)(Qb + (size_t)(q0 + nt * 16 + l16) * HD
                                         + kk * 32 + quad * 8);

    s16x8 ones;
    #pragma unroll
    for (int j = 0; j < 8; j++) ones[j] = (short)0x3F80;   // bf16 1.0

    f32x4 Oacc[2][8];
    #pragma unroll
    for (int mt = 0; mt < 2; mt++)
        #pragma unroll
        for (int dt = 0; dt < 8; dt++)
            Oacc[mt][dt] = f32x4{0.f, 0.f, 0.f, 0.f};
    f32x4 lacc[2] = { f32x4{0.f, 0.f, 0.f, 0.f}, f32x4{0.f, 0.f, 0.f, 0.f} };

    // staging geometry (256 thr, 4 chunks each per matrix; phys thread-const)
    const int kKey = tid >> 4, kC = tid & 15;          // K: 16 keys x 16 chunks
    const int kPhys = kC ^ kKey;                       // key&15 == kKey
    const short* kgp = Kb + (size_t)kKey * HD + kC * 8;
    const int kOff = kKey * 128 + kPhys * 8;
    const int vD = tid >> 3, vC = tid & 7;             // V: 32 d x 8 chunks
    const int vPhys = vC ^ (vD & 7);
    const short* vgp = Vb + (size_t)vD * HW + vC * 8;
    const int vOff = vD * 64 + vPhys * 8;

    s16x8 kreg[4], vreg[4];
    // tile 0 -> regs -> buf0
    #pragma unroll
    for (int i = 0; i < 4; i++) {
        kreg[i] = *(const s16x8*)(kgp + (size_t)(i * 16) * HD);
        vreg[i] = *(const s16x8*)(vgp + (size_t)(i * 32) * HW);
    }
    #pragma unroll
    for (int i = 0; i < 4; i++) {
        *(s16x8*)(&Ks[0][kOff] + i * 16 * 128) = kreg[i];
        *(s16x8*)(&Vs[0][vOff] + i * 32 * 64) = vreg[i];
    }
    // tile 1 -> regs
    #pragma unroll
    for (int i = 0; i < 4; i++) {
        kreg[i] = *(const s16x8*)(kgp + (size_t)(64 + i * 16) * HD);
        vreg[i] = *(const s16x8*)(vgp + 64 + (size_t)(i * 32) * HW);
    }
    __syncthreads();

    #pragma unroll 1
    for (int kt = 0; kt < 16; kt++) {
        const int cur = kt & 1, nxt = cur ^ 1;
        const short* ks = Ks[cur];
        const short* vs = Vs[cur];

        // commit tile kt+1 regs -> other buffer (overlaps compute of tile kt
        // in other waves; safe: nxt buffer last read in iter kt-1, barrier'd)
        #pragma unroll
        for (int i = 0; i < 4; i++) {
            *(s16x8*)(&Ks[nxt][kOff] + i * 16 * 128) = kreg[i];
            *(s16x8*)(&Vs[nxt][vOff] + i * 32 * 64) = vreg[i];
        }
        // prefetch tile kt+2 (wraps at end; harmless L2-hot reload)
        int ktn = (kt + 2) & 15;
        #pragma unroll
        for (int i = 0; i < 4; i++) {
            kreg[i] = *(const s16x8*)(kgp + (size_t)(ktn * 64 + i * 16) * HD);
            vreg[i] = *(const s16x8*)(vgp + ktn * 64 + (size_t)(i * 32) * HW);
        }

        // ---- S^T: 64 keys x 32 qrows (aK shared across both q-tiles)
        f32x4 c[4][2];
        __builtin_amdgcn_s_setprio(1);
        #pragma unroll
        for (int mtp = 0; mtp < 4; mtp++) {
            s16x8 aK[4];
            #pragma unroll
            for (int kk = 0; kk < 4; kk++)
                aK[kk] = *(const s16x8*)(ks + (mtp * 16 + l16) * 128
                                         + (((kk * 4 + quad) ^ l16) * 8));
            c[mtp][0] = f32x4{0.f, 0.f, 0.f, 0.f};
            c[mtp][1] = f32x4{0.f, 0.f, 0.f, 0.f};
            #pragma unroll
            for (int kk = 0; kk < 4; kk++) {
                c[mtp][0] = __builtin_amdgcn_mfma_f32_16x16x32_bf16(
                    aK[kk], bQ[0][kk], c[mtp][0], 0, 0, 0);
                c[mtp][1] = __builtin_amdgcn_mfma_f32_16x16x32_bf16(
                    aK[kk], bQ[1][kk], c[mtp][1], 0, 0, 0);
            }
        }
        __builtin_amdgcn_s_setprio(0);

        // ---- P = exp2(S') packed ENTIRELY in registers (V rows permuted to
        //      match the C-layout keys each lane holds). Two 32-key halves.
        #pragma unroll
        for (int h = 0; h < 2; h++) {
            s16x8 aP[2];
            #pragma unroll
            for (int mt = 0; mt < 2; mt++) {
                f32x4 e0 = c[2 * h][mt], e1 = c[2 * h + 1][mt];
                aP[mt] = s16x8{
                    f2bf(__builtin_amdgcn_exp2f(e0[0])),
                    f2bf(__builtin_amdgcn_exp2f(e0[1])),
                    f2bf(__builtin_amdgcn_exp2f(e0[2])),
                    f2bf(__builtin_amdgcn_exp2f(e0[3])),
                    f2bf(__builtin_amdgcn_exp2f(e1[0])),
                    f2bf(__builtin_amdgcn_exp2f(e1[1])),
                    f2bf(__builtin_amdgcn_exp2f(e1[2])),
                    f2bf(__builtin_amdgcn_exp2f(e1[3])) };
            }

            __builtin_amdgcn_s_setprio(1);
            #pragma unroll
            for (int mt = 0; mt < 2; mt++)
                lacc[mt] = __builtin_amdgcn_mfma_f32_16x16x32_bf16(
                    aP[mt], ones, lacc[mt], 0, 0, 0);

            #pragma unroll
            for (int dt = 0; dt < 8; dt++) {
                s16x8 bV = *(const s16x8*)(vs + (dt * 16 + l16) * 64
                                           + (((h * 4 + quad) ^ (l16 & 7)) * 8));
                #pragma unroll
                for (int mt = 0; mt < 2; mt++)
                    Oacc[mt][dt] = __builtin_amdgcn_mfma_f32_16x16x32_bf16(
                        aP[mt], bV, Oacc[mt][dt], 0, 0, 0);
            }
            __builtin_amdgcn_s_setprio(0);
        }
        __syncthreads();   // single barrier per iter: frees nxt for kt+1
    }

    // epilogue: O/l, stored transposed -> out[b][h][d][p] FP32
    float* ob = out + (size_t)bh * (HD * HW);
    #pragma unroll
    for (int mt = 0; mt < 2; mt++) {
        float inv[4];
        #pragma unroll
        for (int r = 0; r < 4; r++) inv[r] = __builtin_amdgcn_rcpf(lacc[mt][r]);
        int prow = q0 + mt * 16 + quad * 4;
        #pragma unroll
        for (int dt = 0; dt < 8; dt++) {
            int d = dt * 16 + l16;
            f32x4 o = Oacc[mt][dt];
            float4 o4 = { o[0] * inv[0], o[1] * inv[1],
                          o[2] * inv[2], o[3] * inv[3] };
            *reinterpret_cast<float4*>(ob + (size_t)d * HW + prow) = o4;
        }
    }
}

// ---------------------------------------------------------------------------
extern "C" void kernel_launch(void* const* d_in, const int* in_sizes, int n_in,
                              void* d_out, int out_size, void* d_ws, size_t ws_size,
                              hipStream_t stream) {
    const float* x  = (const float*)d_in[0];
    const float* w  = (const float*)d_in[1];
    const float* ph = (const float*)d_in[2];
    const float* pw = (const float*)d_in[3];

    const size_t BHPD = (size_t)NB * NH * HW * HD;   // 8,388,608 elems
    short* Q    = (short*)d_ws;
    short* Kp   = Q + BHPD;
    short* Vt   = Kp + BHPD;
    short* xT   = Vt + BHPD;
    short* Wb   = xT + (size_t)NB * HW * CIN;
    float* outp = (float*)d_out;

    prep_xw<<<dim3(NB * 16 * 32 + 768), 256, 0, stream>>>(x, w, xT, Wb);
    qkv_proj<<<dim3(8, 12, NB), 256, 0, stream>>>(xT, Wb, ph, pw, Q, Kp, Vt);
    attn_fused<<<dim3(512), 256, 0, stream>>>(Q, Kp, Vt, outp);
}